// Round 2
// baseline (2998.680 us; speedup 1.0000x reference)
//
#include <hip/hip_runtime.h>
#include <hip/hip_bf16.h>
#include <cstddef>

__device__ __forceinline__ float  fmah(float a, float b, float c)  { return fmaf(a, b, c); }
__device__ __forceinline__ double fmah(double a, double b, double c){ return fma(a, b, c); }

// ---------------------------------------------------------------------------
// fp32 register-tiled GEMM: C[M,N] = op(A[M,K] @ W[K,N] + bias), row-major.
// ACC selects accumulator precision (float for speed, double for the z_e
// GEMM feeding the VQ argmin, where exactness decides near-tie indices).
// ---------------------------------------------------------------------------
template<int BM, int BN, int BK, int TM, int TN, bool RELU, typename ACC = float>
__global__ __launch_bounds__((BM / TM) * (BN / TN))
void gemm_bias(const float* __restrict__ A, const float* __restrict__ W,
               const float* __restrict__ bias, float* __restrict__ C,
               int M, int N, int K)
{
    constexpr int TX = BN / TN;
    constexpr int TY = BM / TM;
    constexpr int NT = TX * TY;
    constexpr int RG = TM / 4;          // row groups of 4
    constexpr int CG = TN / 4;          // col groups of 4
    constexpr int RS = BM / RG;         // row group stride
    constexpr int CS = BN / CG;         // col group stride
    constexpr int AV = (BM * BK) / (NT * 4);
    constexpr int BV = (BK * BN) / (NT * 4);
    static_assert(AV >= 1 && BV >= 1, "tile too small for vector staging");

    __shared__ alignas(16) float As[BK][BM];   // A tile transposed: As[k][m]
    __shared__ alignas(16) float Bs[BK][BN];   // W tile: Bs[k][n]

    const int tid = threadIdx.x;
    const int tx  = tid % TX;
    const int ty  = tid / TX;
    const int bm  = blockIdx.y * BM;
    const int bn  = blockIdx.x * BN;

    ACC acc[TM][TN];
#pragma unroll
    for (int i = 0; i < TM; ++i)
#pragma unroll
        for (int j = 0; j < TN; ++j) acc[i][j] = (ACC)0;

    for (int k0 = 0; k0 < K; k0 += BK) {
        // stage A tile (transposed into LDS)
#pragma unroll
        for (int v = 0; v < AV; ++v) {
            int idx = (tid + v * NT) * 4;
            int r = idx / BK, c = idx % BK;
            float4 f = *reinterpret_cast<const float4*>(
                &A[(size_t)(bm + r) * K + (k0 + c)]);
            As[c + 0][r] = f.x; As[c + 1][r] = f.y;
            As[c + 2][r] = f.z; As[c + 3][r] = f.w;
        }
        // stage W tile
#pragma unroll
        for (int v = 0; v < BV; ++v) {
            int idx = (tid + v * NT) * 4;
            int r = idx / BN, c = idx % BN;
            *reinterpret_cast<float4*>(&Bs[r][c]) =
                *reinterpret_cast<const float4*>(&W[(size_t)(k0 + r) * N + (bn + c)]);
        }
        __syncthreads();

#pragma unroll
        for (int kk = 0; kk < BK; ++kk) {
            float a[TM], b[TN];
#pragma unroll
            for (int rg = 0; rg < RG; ++rg) {
                float4 f = *reinterpret_cast<const float4*>(&As[kk][rg * RS + ty * 4]);
                a[rg * 4 + 0] = f.x; a[rg * 4 + 1] = f.y;
                a[rg * 4 + 2] = f.z; a[rg * 4 + 3] = f.w;
            }
#pragma unroll
            for (int cg = 0; cg < CG; ++cg) {
                float4 f = *reinterpret_cast<const float4*>(&Bs[kk][cg * CS + tx * 4]);
                b[cg * 4 + 0] = f.x; b[cg * 4 + 1] = f.y;
                b[cg * 4 + 2] = f.z; b[cg * 4 + 3] = f.w;
            }
#pragma unroll
            for (int i = 0; i < TM; ++i)
#pragma unroll
                for (int j = 0; j < TN; ++j)
                    acc[i][j] = fmah((ACC)a[i], (ACC)b[j], acc[i][j]);
        }
        __syncthreads();
    }

    // epilogue: round acc to fp32, add bias (+ relu), float4 stores
#pragma unroll
    for (int rg = 0; rg < RG; ++rg)
#pragma unroll
        for (int ii = 0; ii < 4; ++ii) {
            const size_t r = (size_t)bm + rg * RS + ty * 4 + ii;
#pragma unroll
            for (int cg = 0; cg < CG; ++cg) {
                const int c = bn + cg * CS + tx * 4;
                float4 bv = *reinterpret_cast<const float4*>(&bias[c]);
                float4 o;
                o.x = (float)acc[rg * 4 + ii][cg * 4 + 0] + bv.x;
                o.y = (float)acc[rg * 4 + ii][cg * 4 + 1] + bv.y;
                o.z = (float)acc[rg * 4 + ii][cg * 4 + 2] + bv.z;
                o.w = (float)acc[rg * 4 + ii][cg * 4 + 3] + bv.w;
                if (RELU) {
                    o.x = fmaxf(o.x, 0.f); o.y = fmaxf(o.y, 0.f);
                    o.z = fmaxf(o.z, 0.f); o.w = fmaxf(o.w, 0.f);
                }
                *reinterpret_cast<float4*>(&C[r * N + c]) = o;
            }
        }
}

// ---------------------------------------------------------------------------
// VQ: per-row nearest codebook entry (256 entries, D=64) + gather.
// d2 computed in fp64 (exact at fp32-input granularity) so the argmin is the
// TRUE first-min — np (CPU BLAS) and jax (GPU) agree with each other, hence
// both sit at the true argmin; matching truth matches both.
// One row per thread; codebook staged in LDS (broadcast reads), per-entry
// |c|^2 precomputed in fp64.
// ---------------------------------------------------------------------------
__global__ __launch_bounds__(256)
void vq_gather(const float* __restrict__ Z, const float* __restrict__ CB,
               float* __restrict__ OUT, int M)
{
    __shared__ alignas(16) float cb[256 * 64];   // 64 KB, [entry][dim]
    __shared__ double ccs[256];                  // |c|^2 per entry (fp64)

    const int tid = threadIdx.x;
    const int row = blockIdx.x * 256 + tid;

    // cooperative codebook load (coalesced float4)
#pragma unroll
    for (int v = 0; v < 16; ++v) {
        int idx = (tid + v * 256) * 4;
        *reinterpret_cast<float4*>(&cb[idx]) =
            *reinterpret_cast<const float4*>(&CB[idx]);
    }
    __syncthreads();

    // per-entry |c|^2 in fp64 (thread tid handles entry tid)
    {
        double cc = 0.0;
        const float* c = &cb[tid * 64];
#pragma unroll
        for (int d = 0; d < 64; ++d) { double cd = (double)c[d]; cc = fma(cd, cd, cc); }
        ccs[tid] = cc;
    }

    // load this thread's z row
    float z[64];
#pragma unroll
    for (int v = 0; v < 16; ++v) {
        float4 f = *reinterpret_cast<const float4*>(&Z[(size_t)row * 64 + v * 4]);
        z[v * 4 + 0] = f.x; z[v * 4 + 1] = f.y; z[v * 4 + 2] = f.z; z[v * 4 + 3] = f.w;
    }
    double xx = 0.0;
#pragma unroll
    for (int d = 0; d < 64; ++d) { double zd = (double)z[d]; xx = fma(zd, zd, xx); }
    __syncthreads();

    // scan all 256 entries, exact d2, first-min
    double best = 1.0e300;
    int    bi   = 0;
    for (int e = 0; e < 256; ++e) {
        const float* c = &cb[e * 64];
        double dot = 0.0;
#pragma unroll
        for (int d = 0; d < 64; ++d)
            dot = fma((double)z[d], (double)c[d], dot);
        double d2 = (xx - 2.0 * dot) + ccs[e];
        if (d2 < best) { best = d2; bi = e; }
    }

    // gather codebook[bi] -> OUT row
    {
        const float* src = &cb[bi * 64];
        float* dst = &OUT[(size_t)row * 64];
#pragma unroll
        for (int v = 0; v < 16; ++v)
            *reinterpret_cast<float4*>(dst + v * 4) =
                *reinterpret_cast<const float4*>(src + v * 4);
    }
}

// ---------------------------------------------------------------------------
extern "C" void kernel_launch(void* const* d_in, const int* in_sizes, int n_in,
                              void* d_out, int out_size, void* d_ws, size_t ws_size,
                              hipStream_t stream)
{
    const float* X  = (const float*)d_in[0];
    const float* W0 = (const float*)d_in[1];
    const float* b0 = (const float*)d_in[2];
    const float* W1 = (const float*)d_in[3];
    const float* b1 = (const float*)d_in[4];
    const float* W2 = (const float*)d_in[5];
    const float* b2 = (const float*)d_in[6];
    const float* CB = (const float*)d_in[7];
    const float* W3 = (const float*)d_in[8];
    const float* b3 = (const float*)d_in[9];
    const float* W4 = (const float*)d_in[10];
    const float* b4 = (const float*)d_in[11];
    const float* W5 = (const float*)d_in[12];
    const float* b5 = (const float*)d_in[13];

    const int D_in = 256, H = 512, R = 64, S = 512, NA = 8;
    const int Mtot = in_sizes[0] / D_in;          // 131072

    float* recon = (float*)d_out;                          // [Mtot/8, 512]
    float* ze    = recon + (size_t)(Mtot / NA) * S;        // [Mtot, 64]
    float* remb  = ze + (size_t)Mtot * R;                  // [Mtot, 64]

    // adaptive chunking: scratch = 2 chunk activations + rec2
    int nc = 2;
    while (nc < 128) {
        size_t Sb = (size_t)(Mtot / nc) * H * sizeof(float);
        if (2 * Sb + Sb / 8 <= ws_size) break;
        nc *= 2;
    }
    const int rpc = Mtot / nc;                    // rows per chunk
    float* wsA = (float*)d_ws;                    // h0 / rec1   [rpc,512]
    float* wsB = wsA + (size_t)rpc * H;           // h1          [rpc,512]
    float* wsC = wsB + (size_t)rpc * H;           // rec2        [rpc/8,512]

    for (int r0 = 0; r0 < Mtot; r0 += rpc) {
        const int M6 = rpc / NA;
        // h0 = relu(X @ W0 + b0)
        gemm_bias<128,128,16,8,8,true><<<dim3(H/128, rpc/128), 256, 0, stream>>>(
            X + (size_t)r0 * D_in, W0, b0, wsA, rpc, H, D_in);
        // h1 = relu(h0 @ W1 + b1)
        gemm_bias<128,128,16,8,8,true><<<dim3(H/128, rpc/128), 256, 0, stream>>>(
            wsA, W1, b1, wsB, rpc, H, H);
        // z_e = h1 @ W2 + b2   (fp64 accumulation -> exact-at-fp32 z_e)
        gemm_bias<64,64,16,4,4,false,double><<<dim3(1, rpc/64), 256, 0, stream>>>(
            wsB, W2, b2, ze + (size_t)r0 * R, rpc, R, H);
        // role_emb (== z_q forward value) -> output zone 2
        vq_gather<<<rpc/256, 256, 0, stream>>>(
            ze + (size_t)r0 * R, CB, remb + (size_t)r0 * R, rpc);
        // rec1 = relu(z_q @ W3 + b3)
        gemm_bias<128,128,16,8,8,true><<<dim3(H/128, rpc/128), 256, 0, stream>>>(
            remb + (size_t)r0 * R, W3, b3, wsA, rpc, H, R);
        // rec2 = relu(rec1.reshape @ W4 + b4)
        gemm_bias<64,64,16,4,4,true><<<dim3(H/64, M6/64), 256, 0, stream>>>(
            wsA, W4, b4, wsC, M6, H, NA * H);
        // recon = rec2 @ W5 + b5 -> output zone 0
        gemm_bias<64,64,16,4,4,false><<<dim3(S/64, M6/64), 256, 0, stream>>>(
            wsC, W5, b5, recon + (size_t)(r0 / NA) * S, M6, S, H);
    }
}

// Round 3
// 2114.390 us; speedup vs baseline: 1.4182x; 1.4182x over previous
//
#include <hip/hip_runtime.h>
#include <hip/hip_bf16.h>
#include <cstddef>

__device__ __forceinline__ float  fmah(float a, float b, float c)  { return fmaf(a, b, c); }
__device__ __forceinline__ double fmah(double a, double b, double c){ return fma(a, b, c); }

__device__ __forceinline__ unsigned short f2bf(float f) {
    union { float f; unsigned int u; } v; v.f = f;
    unsigned int r = (v.u + 0x7fffu + ((v.u >> 16) & 1u)) >> 16;   // RNE
    return (unsigned short)r;
}

typedef __bf16 bf16x8 __attribute__((ext_vector_type(8)));
typedef float  f32x4  __attribute__((ext_vector_type(4)));

// ---------------------------------------------------------------------------
// fp32 register-tiled GEMM (encoder + z_e). ACC=double for the z_e GEMM so
// the VQ argmin sees exact-at-fp32 inputs (tie-break correctness).
// ---------------------------------------------------------------------------
template<int BM, int BN, int BK, int TM, int TN, bool RELU, typename ACC = float>
__global__ __launch_bounds__((BM / TM) * (BN / TN))
void gemm_bias(const float* __restrict__ A, const float* __restrict__ W,
               const float* __restrict__ bias, float* __restrict__ C,
               int M, int N, int K)
{
    constexpr int TX = BN / TN;
    constexpr int TY = BM / TM;
    constexpr int NT = TX * TY;
    constexpr int RG = TM / 4;
    constexpr int CG = TN / 4;
    constexpr int RS = BM / RG;
    constexpr int CS = BN / CG;
    constexpr int AV = (BM * BK) / (NT * 4);
    constexpr int BV = (BK * BN) / (NT * 4);
    static_assert(AV >= 1 && BV >= 1, "tile too small for vector staging");

    __shared__ alignas(16) float As[BK][BM];
    __shared__ alignas(16) float Bs[BK][BN];

    const int tid = threadIdx.x;
    const int tx  = tid % TX;
    const int ty  = tid / TX;
    const int bm  = blockIdx.y * BM;
    const int bn  = blockIdx.x * BN;

    ACC acc[TM][TN];
#pragma unroll
    for (int i = 0; i < TM; ++i)
#pragma unroll
        for (int j = 0; j < TN; ++j) acc[i][j] = (ACC)0;

    for (int k0 = 0; k0 < K; k0 += BK) {
#pragma unroll
        for (int v = 0; v < AV; ++v) {
            int idx = (tid + v * NT) * 4;
            int r = idx / BK, c = idx % BK;
            float4 f = *reinterpret_cast<const float4*>(
                &A[(size_t)(bm + r) * K + (k0 + c)]);
            As[c + 0][r] = f.x; As[c + 1][r] = f.y;
            As[c + 2][r] = f.z; As[c + 3][r] = f.w;
        }
#pragma unroll
        for (int v = 0; v < BV; ++v) {
            int idx = (tid + v * NT) * 4;
            int r = idx / BN, c = idx % BN;
            *reinterpret_cast<float4*>(&Bs[r][c]) =
                *reinterpret_cast<const float4*>(&W[(size_t)(k0 + r) * N + (bn + c)]);
        }
        __syncthreads();

#pragma unroll
        for (int kk = 0; kk < BK; ++kk) {
            float a[TM], b[TN];
#pragma unroll
            for (int rg = 0; rg < RG; ++rg) {
                float4 f = *reinterpret_cast<const float4*>(&As[kk][rg * RS + ty * 4]);
                a[rg * 4 + 0] = f.x; a[rg * 4 + 1] = f.y;
                a[rg * 4 + 2] = f.z; a[rg * 4 + 3] = f.w;
            }
#pragma unroll
            for (int cg = 0; cg < CG; ++cg) {
                float4 f = *reinterpret_cast<const float4*>(&Bs[kk][cg * CS + tx * 4]);
                b[cg * 4 + 0] = f.x; b[cg * 4 + 1] = f.y;
                b[cg * 4 + 2] = f.z; b[cg * 4 + 3] = f.w;
            }
#pragma unroll
            for (int i = 0; i < TM; ++i)
#pragma unroll
                for (int j = 0; j < TN; ++j)
                    acc[i][j] = fmah((ACC)a[i], (ACC)b[j], acc[i][j]);
        }
        __syncthreads();
    }

#pragma unroll
    for (int rg = 0; rg < RG; ++rg)
#pragma unroll
        for (int ii = 0; ii < 4; ++ii) {
            const size_t r = (size_t)bm + rg * RS + ty * 4 + ii;
#pragma unroll
            for (int cg = 0; cg < CG; ++cg) {
                const int c = bn + cg * CS + tx * 4;
                float4 bv = *reinterpret_cast<const float4*>(&bias[c]);
                float4 o;
                o.x = (float)acc[rg * 4 + ii][cg * 4 + 0] + bv.x;
                o.y = (float)acc[rg * 4 + ii][cg * 4 + 1] + bv.y;
                o.z = (float)acc[rg * 4 + ii][cg * 4 + 2] + bv.z;
                o.w = (float)acc[rg * 4 + ii][cg * 4 + 3] + bv.w;
                if (RELU) {
                    o.x = fmaxf(o.x, 0.f); o.y = fmaxf(o.y, 0.f);
                    o.z = fmaxf(o.z, 0.f); o.w = fmaxf(o.w, 0.f);
                }
                *reinterpret_cast<float4*>(&C[r * N + c]) = o;
            }
        }
}

// ---------------------------------------------------------------------------
// bf16 MFMA GEMM: C[M,N] = op(A[M,K] @ Bt[N,K]^T + bias).
// A, Bt bf16 row-major (Bt = W^T, so both operand fragments are contiguous
// 8-elem k-runs -> ds_read_b128). 128x128 tile, BK=64, 4 waves, each wave a
// 64x64 sub-tile of 4x4 16x16x32 fragments. LDS rows padded +8 bf16 (16B) so
// fragment reads land ~2-way on banks (free, m136).
// Fragment layouts (gfx950, m89-verified): A lane l = row(l&15), k=(l>>4)*8+j;
// B lane l = col(l&15), same k; C/D col=lane&15, row=(lane>>4)*4+reg.
// ---------------------------------------------------------------------------
template<bool RELU, bool OUT_BF16>
__global__ __launch_bounds__(256)
void gemm_mfma_bt(const unsigned short* __restrict__ A,
                  const unsigned short* __restrict__ Bt,
                  const float* __restrict__ bias,
                  void* __restrict__ Cv, int M, int N, int K)
{
    constexpr int BK  = 64;
    constexpr int LDP = BK + 8;                 // padded LDS row (bf16)

    __shared__ alignas(16) unsigned short Asl[128][LDP];
    __shared__ alignas(16) unsigned short Bsl[128][LDP];

    const int tid  = threadIdx.x;
    const int lane = tid & 63;
    const int w    = tid >> 6;                  // wave 0..3
    const int wr   = (w >> 1) * 64;             // wave row offset
    const int wc   = (w & 1) * 64;              // wave col offset
    const int bm   = blockIdx.y * 128;
    const int bn   = blockIdx.x * 128;

    f32x4 acc[4][4];
#pragma unroll
    for (int m = 0; m < 4; ++m)
#pragma unroll
        for (int n = 0; n < 4; ++n) acc[m][n] = (f32x4){0.f, 0.f, 0.f, 0.f};

    const int sr = tid >> 1;                    // staging row 0..127
    const int sc = (tid & 1) * 32;              // staging col half

    for (int k0 = 0; k0 < K; k0 += BK) {
        // ---- stage A,Bt tiles: 2 threads/row, 4x16B each ----
        {
            const float4* ga = reinterpret_cast<const float4*>(
                &A[(size_t)(bm + sr) * K + k0 + sc]);
            const float4* gb = reinterpret_cast<const float4*>(
                &Bt[(size_t)(bn + sr) * K + k0 + sc]);
            float4 va0 = ga[0], va1 = ga[1], va2 = ga[2], va3 = ga[3];
            float4 vb0 = gb[0], vb1 = gb[1], vb2 = gb[2], vb3 = gb[3];
            float4* da = reinterpret_cast<float4*>(&Asl[sr][sc]);
            float4* db = reinterpret_cast<float4*>(&Bsl[sr][sc]);
            da[0] = va0; da[1] = va1; da[2] = va2; da[3] = va3;
            db[0] = vb0; db[1] = vb1; db[2] = vb2; db[3] = vb3;
        }
        __syncthreads();

#pragma unroll
        for (int ks = 0; ks < 2; ++ks) {
            bf16x8 af[4], bf[4];
            const int kc = ks * 32 + (lane >> 4) * 8;
#pragma unroll
            for (int m = 0; m < 4; ++m)
                af[m] = *reinterpret_cast<const bf16x8*>(
                    &Asl[wr + m * 16 + (lane & 15)][kc]);
#pragma unroll
            for (int n = 0; n < 4; ++n)
                bf[n] = *reinterpret_cast<const bf16x8*>(
                    &Bsl[wc + n * 16 + (lane & 15)][kc]);
#pragma unroll
            for (int m = 0; m < 4; ++m)
#pragma unroll
                for (int n = 0; n < 4; ++n)
                    acc[m][n] = __builtin_amdgcn_mfma_f32_16x16x32_bf16(
                        af[m], bf[n], acc[m][n], 0, 0, 0);
        }
        __syncthreads();
    }

    // ---- epilogue ----
#pragma unroll
    for (int m = 0; m < 4; ++m)
#pragma unroll
        for (int n = 0; n < 4; ++n) {
            const int col = bn + wc + n * 16 + (lane & 15);
            const float bv = bias[col];
#pragma unroll
            for (int q = 0; q < 4; ++q) {
                const int row = bm + wr + m * 16 + (lane >> 4) * 4 + q;
                float v = acc[m][n][q] + bv;
                if (RELU) v = fmaxf(v, 0.f);
                if (OUT_BF16)
                    reinterpret_cast<unsigned short*>(Cv)[(size_t)row * N + col] = f2bf(v);
                else
                    reinterpret_cast<float*>(Cv)[(size_t)row * N + col] = v;
            }
        }
}

// ---------------------------------------------------------------------------
// W[K][N] fp32 -> Wt[N][K] bf16 (write-coalesced; reads L2-absorbed, tiny)
// ---------------------------------------------------------------------------
__global__ __launch_bounds__(256)
void transpose_bf16(const float* __restrict__ W, unsigned short* __restrict__ Wt,
                    int K, int N)
{
    int idx = blockIdx.x * 256 + threadIdx.x;           // idx = n*K + k
    if (idx >= K * N) return;
    int n = idx / K, k = idx % K;
    Wt[idx] = f2bf(W[(size_t)k * N + n]);
}

// fp32 -> bf16 elementwise (z_q), 8 elems/thread
__global__ __launch_bounds__(256)
void conv_bf16(const float* __restrict__ src, unsigned short* __restrict__ dst, int n8)
{
    int i = blockIdx.x * 256 + threadIdx.x;
    if (i >= n8) return;
    float4 a = *reinterpret_cast<const float4*>(&src[i * 8]);
    float4 b = *reinterpret_cast<const float4*>(&src[i * 8 + 4]);
    unsigned short o[8] = { f2bf(a.x), f2bf(a.y), f2bf(a.z), f2bf(a.w),
                            f2bf(b.x), f2bf(b.y), f2bf(b.z), f2bf(b.w) };
    *reinterpret_cast<float4*>(&dst[i * 8]) = *reinterpret_cast<float4*>(o);
}

// ---------------------------------------------------------------------------
// VQ: exact (fp64) nearest-codebook + gather. One row/thread, codebook in LDS
// (broadcast float4 reads -> fp64 FMA-bound, ~55us floor at fp64 rate).
// ---------------------------------------------------------------------------
__global__ __launch_bounds__(256)
void vq_gather(const float* __restrict__ Z, const float* __restrict__ CB,
               float* __restrict__ OUT, int M)
{
    __shared__ alignas(16) float cb[256 * 64];
    __shared__ double ccs[256];

    const int tid = threadIdx.x;
    const int row = blockIdx.x * 256 + tid;

#pragma unroll
    for (int v = 0; v < 16; ++v) {
        int idx = (tid + v * 256) * 4;
        *reinterpret_cast<float4*>(&cb[idx]) =
            *reinterpret_cast<const float4*>(&CB[idx]);
    }
    __syncthreads();

    {
        double cc = 0.0;
        const float* c = &cb[tid * 64];
#pragma unroll
        for (int d = 0; d < 64; ++d) { double cd = (double)c[d]; cc = fma(cd, cd, cc); }
        ccs[tid] = cc;
    }

    float z[64];
#pragma unroll
    for (int v = 0; v < 16; ++v) {
        float4 f = *reinterpret_cast<const float4*>(&Z[(size_t)row * 64 + v * 4]);
        z[v * 4 + 0] = f.x; z[v * 4 + 1] = f.y; z[v * 4 + 2] = f.z; z[v * 4 + 3] = f.w;
    }
    double xx = 0.0;
#pragma unroll
    for (int d = 0; d < 64; ++d) { double zd = (double)z[d]; xx = fma(zd, zd, xx); }
    __syncthreads();

    double best = 1.0e300;
    int    bi   = 0;
    for (int e = 0; e < 256; ++e) {
        const float4* c4 = reinterpret_cast<const float4*>(&cb[e * 64]);
        double dot = 0.0;
#pragma unroll
        for (int v = 0; v < 16; ++v) {
            float4 f = c4[v];                    // broadcast b128, conflict-free
            dot = fma((double)z[v * 4 + 0], (double)f.x, dot);
            dot = fma((double)z[v * 4 + 1], (double)f.y, dot);
            dot = fma((double)z[v * 4 + 2], (double)f.z, dot);
            dot = fma((double)z[v * 4 + 3], (double)f.w, dot);
        }
        double d2 = (xx - 2.0 * dot) + ccs[e];
        if (d2 < best) { best = d2; bi = e; }
    }

    {
        const float* src = &cb[bi * 64];
        float* dst = &OUT[(size_t)row * 64];
#pragma unroll
        for (int v = 0; v < 16; ++v)
            *reinterpret_cast<float4*>(dst + v * 4) =
                *reinterpret_cast<const float4*>(src + v * 4);
    }
}

// ---------------------------------------------------------------------------
extern "C" void kernel_launch(void* const* d_in, const int* in_sizes, int n_in,
                              void* d_out, int out_size, void* d_ws, size_t ws_size,
                              hipStream_t stream)
{
    const float* X  = (const float*)d_in[0];
    const float* W0 = (const float*)d_in[1];
    const float* b0 = (const float*)d_in[2];
    const float* W1 = (const float*)d_in[3];
    const float* b1 = (const float*)d_in[4];
    const float* W2 = (const float*)d_in[5];
    const float* b2 = (const float*)d_in[6];
    const float* CB = (const float*)d_in[7];
    const float* W3 = (const float*)d_in[8];
    const float* b3 = (const float*)d_in[9];
    const float* W4 = (const float*)d_in[10];
    const float* b4 = (const float*)d_in[11];
    const float* W5 = (const float*)d_in[12];
    const float* b5 = (const float*)d_in[13];

    const int D_in = 256, H = 512, R = 64, S = 512, NA = 8;
    const int Mtot = in_sizes[0] / D_in;          // 131072

    float* recon = (float*)d_out;
    float* ze    = recon + (size_t)(Mtot / NA) * S;
    float* remb  = ze + (size_t)Mtot * R;

    // ---- workspace carve-up ----
    // fixed: bf16-transposed weights; per-chunk: h0/h1 fp32 (reused as bf16
    // rec1/rec2 outputs), z_q bf16.
    char* p = (char*)d_ws;
    unsigned short* W3t = (unsigned short*)p;  p += (size_t)H * R * 2;        // [512,64]
    unsigned short* W4t = (unsigned short*)p;  p += (size_t)H * (NA * H) * 2; // [512,4096]
    unsigned short* W5t = (unsigned short*)p;  p += (size_t)S * H * 2;        // [512,512]
    size_t fixed = (size_t)(p - (char*)d_ws);
    fixed = (fixed + 255) & ~(size_t)255;

    int nc = 2;
    while (nc < 128) {
        size_t rpcT = (size_t)Mtot / nc;
        size_t need = fixed + 2 * (rpcT * H * 4) + rpcT * R * 2 + 512;
        if (need <= ws_size) break;
        nc *= 2;
    }
    const int rpc = Mtot / nc;
    char* q = (char*)d_ws + fixed;
    float* wsA = (float*)q;                     // h0 fp32 / rec1 bf16 (alias)
    float* wsB = wsA + (size_t)rpc * H;         // h1 fp32 / rec2 bf16 (alias)
    unsigned short* zqb = (unsigned short*)(wsB + (size_t)rpc * H);  // [rpc,64] bf16
    unsigned short* rec1b = (unsigned short*)wsA;
    unsigned short* rec2b = (unsigned short*)wsB;

    // ---- one-time weight transposes (per launch; deterministic) ----
    transpose_bf16<<<(H * R + 255) / 256, 256, 0, stream>>>(W3, W3t, R, H);
    transpose_bf16<<<(H * NA * H + 255) / 256, 256, 0, stream>>>(W4, W4t, NA * H, H);
    transpose_bf16<<<(S * H + 255) / 256, 256, 0, stream>>>(W5, W5t, H, S);

    for (int r0 = 0; r0 < Mtot; r0 += rpc) {
        const int M6 = rpc / NA;
        // encoder (fp32; feeds tie-sensitive argmin)
        gemm_bias<128,128,16,8,8,true><<<dim3(H/128, rpc/128), 256, 0, stream>>>(
            X + (size_t)r0 * D_in, W0, b0, wsA, rpc, H, D_in);
        gemm_bias<128,128,16,8,8,true><<<dim3(H/128, rpc/128), 256, 0, stream>>>(
            wsA, W1, b1, wsB, rpc, H, H);
        gemm_bias<64,64,16,4,4,false,double><<<dim3(1, rpc/64), 256, 0, stream>>>(
            wsB, W2, b2, ze + (size_t)r0 * R, rpc, R, H);
        // exact VQ -> role_emb (== z_q forward value)
        vq_gather<<<rpc/256, 256, 0, stream>>>(
            ze + (size_t)r0 * R, CB, remb + (size_t)r0 * R, rpc);
        // decoder (bf16 MFMA; loose threshold)
        conv_bf16<<<(rpc * R / 8 + 255) / 256, 256, 0, stream>>>(
            remb + (size_t)r0 * R, zqb, rpc * R / 8);
        gemm_mfma_bt<true, true><<<dim3(H/128, rpc/128), 256, 0, stream>>>(
            zqb, W3t, b3, rec1b, rpc, H, R);
        gemm_mfma_bt<true, true><<<dim3(H/128, M6/128), 256, 0, stream>>>(
            rec1b, W4t, b4, rec2b, M6, H, NA * H);
        gemm_mfma_bt<false, false><<<dim3(S/128, M6/128), 256, 0, stream>>>(
            rec2b, W5t, b5, recon + (size_t)(r0 / NA) * S, M6, S, H);
    }
}

// Round 4
// 1673.835 us; speedup vs baseline: 1.7915x; 1.2632x over previous
//
#include <hip/hip_runtime.h>
#include <hip/hip_bf16.h>
#include <cstddef>

__device__ __forceinline__ unsigned short f2bf(float f) {
    union { float f; unsigned int u; } v; v.f = f;
    unsigned int r = (v.u + 0x7fffu + ((v.u >> 16) & 1u)) >> 16;   // RNE
    return (unsigned short)r;
}

typedef __bf16    bf16x8 __attribute__((ext_vector_type(8)));
typedef float     f32x4  __attribute__((ext_vector_type(4)));
typedef _Float16  f16x8  __attribute__((ext_vector_type(8)));
typedef _Float16  f16x4  __attribute__((ext_vector_type(4)));

// fp32 -> fp16 (hi, lo*4096) split. hi + 2^-12*lo reconstructs v to ~2^-23
// relative. lo is scaled by 2^12 so it stays in fp16 NORMAL range even for
// small weights (0.02 scale) -> robust whether or not MFMA flushes denormals.
__device__ __forceinline__ void fsplit(float v, _Float16& hi, _Float16& lo) {
    hi = (_Float16)v;
    lo = (_Float16)((v - (float)hi) * 4096.0f);
}

// ---------------------------------------------------------------------------
// Split-fp16 MFMA GEMM (encoder): C = relu(A @ Bt^T + bias), where A and Bt
// are (hi, lo*2^12) fp16 plane pairs. acc0 = Ah*Bh; acc1 = Ah*Bl + Al*Bh;
// C = acc0 + 2^-12*acc1  ->  fp32-grade products at MFMA rate/3.
// Output written as fp16 pair planes (feeds the next split GEMM / z_e).
// 128x128 tile, BK=64, 4 waves x 64x64, 16x16x32 f16 MFMA.
// ---------------------------------------------------------------------------
__global__ __launch_bounds__(256)
void gemm_split_f16(const _Float16* __restrict__ Ahi, const _Float16* __restrict__ Alo,
                    const _Float16* __restrict__ Bhi, const _Float16* __restrict__ Blo,
                    const float* __restrict__ bias,
                    _Float16* __restrict__ Chi, _Float16* __restrict__ Clo,
                    int M, int N, int K)
{
    constexpr int BK  = 64;
    constexpr int LDP = BK + 8;

    __shared__ alignas(16) _Float16 Ah[128][LDP];
    __shared__ alignas(16) _Float16 Al[128][LDP];
    __shared__ alignas(16) _Float16 Bh[128][LDP];
    __shared__ alignas(16) _Float16 Bl[128][LDP];

    const int tid  = threadIdx.x;
    const int lane = tid & 63;
    const int w    = tid >> 6;
    const int wr   = (w >> 1) * 64;
    const int wc   = (w & 1) * 64;
    const int bm   = blockIdx.y * 128;
    const int bn   = blockIdx.x * 128;

    f32x4 acc0[4][4], acc1[4][4];
#pragma unroll
    for (int m = 0; m < 4; ++m)
#pragma unroll
        for (int n = 0; n < 4; ++n) {
            acc0[m][n] = (f32x4){0.f, 0.f, 0.f, 0.f};
            acc1[m][n] = (f32x4){0.f, 0.f, 0.f, 0.f};
        }

    const int sr = tid >> 1;
    const int sc = (tid & 1) * 32;

    for (int k0 = 0; k0 < K; k0 += BK) {
        {   // stage 4 plane tiles: each thread 32 f16 (4x16B) per plane
            const size_t ga = (size_t)(bm + sr) * K + k0 + sc;
            const size_t gb = (size_t)(bn + sr) * K + k0 + sc;
            const float4* pAh = reinterpret_cast<const float4*>(Ahi + ga);
            const float4* pAl = reinterpret_cast<const float4*>(Alo + ga);
            const float4* pBh = reinterpret_cast<const float4*>(Bhi + gb);
            const float4* pBl = reinterpret_cast<const float4*>(Blo + gb);
            float4 vah[4], val[4], vbh[4], vbl[4];
#pragma unroll
            for (int i = 0; i < 4; ++i) { vah[i] = pAh[i]; val[i] = pAl[i]; }
#pragma unroll
            for (int i = 0; i < 4; ++i) { vbh[i] = pBh[i]; vbl[i] = pBl[i]; }
            float4* dAh = reinterpret_cast<float4*>(&Ah[sr][sc]);
            float4* dAl = reinterpret_cast<float4*>(&Al[sr][sc]);
            float4* dBh = reinterpret_cast<float4*>(&Bh[sr][sc]);
            float4* dBl = reinterpret_cast<float4*>(&Bl[sr][sc]);
#pragma unroll
            for (int i = 0; i < 4; ++i) { dAh[i] = vah[i]; dAl[i] = val[i]; }
#pragma unroll
            for (int i = 0; i < 4; ++i) { dBh[i] = vbh[i]; dBl[i] = vbl[i]; }
        }
        __syncthreads();

#pragma unroll
        for (int ks = 0; ks < 2; ++ks) {
            const int kc = ks * 32 + (lane >> 4) * 8;
            f16x8 ah[4], bh[4];
#pragma unroll
            for (int m = 0; m < 4; ++m)
                ah[m] = *reinterpret_cast<const f16x8*>(&Ah[wr + m * 16 + (lane & 15)][kc]);
#pragma unroll
            for (int n = 0; n < 4; ++n)
                bh[n] = *reinterpret_cast<const f16x8*>(&Bh[wc + n * 16 + (lane & 15)][kc]);
#pragma unroll
            for (int m = 0; m < 4; ++m)
#pragma unroll
                for (int n = 0; n < 4; ++n)
                    acc0[m][n] = __builtin_amdgcn_mfma_f32_16x16x32_f16(
                        ah[m], bh[n], acc0[m][n], 0, 0, 0);
            f16x8 bl[4];
#pragma unroll
            for (int n = 0; n < 4; ++n)
                bl[n] = *reinterpret_cast<const f16x8*>(&Bl[wc + n * 16 + (lane & 15)][kc]);
#pragma unroll
            for (int m = 0; m < 4; ++m)
#pragma unroll
                for (int n = 0; n < 4; ++n)
                    acc1[m][n] = __builtin_amdgcn_mfma_f32_16x16x32_f16(
                        ah[m], bl[n], acc1[m][n], 0, 0, 0);
            f16x8 al[4];
#pragma unroll
            for (int m = 0; m < 4; ++m)
                al[m] = *reinterpret_cast<const f16x8*>(&Al[wr + m * 16 + (lane & 15)][kc]);
#pragma unroll
            for (int m = 0; m < 4; ++m)
#pragma unroll
                for (int n = 0; n < 4; ++n)
                    acc1[m][n] = __builtin_amdgcn_mfma_f32_16x16x32_f16(
                        al[m], bh[n], acc1[m][n], 0, 0, 0);
        }
        __syncthreads();
    }

    // epilogue: combine scales, bias, relu, write fp16 pair planes
#pragma unroll
    for (int m = 0; m < 4; ++m)
#pragma unroll
        for (int n = 0; n < 4; ++n) {
            const int col = bn + wc + n * 16 + (lane & 15);
            const float bv = bias[col];
#pragma unroll
            for (int q = 0; q < 4; ++q) {
                const int row = bm + wr + m * 16 + (lane >> 4) * 4 + q;
                float v = acc0[m][n][q] + 2.44140625e-4f * acc1[m][n][q] + bv;
                v = fmaxf(v, 0.f);
                _Float16 hi, lo; fsplit(v, hi, lo);
                Chi[(size_t)row * N + col] = hi;
                Clo[(size_t)row * N + col] = lo;
            }
        }
}

// ---------------------------------------------------------------------------
// z_e GEMM: fp64 accumulation (exact-at-fp32 -> safe VQ argmin + tight
// output-1 check). A consumed from fp16 pair planes, W2 fp32. 64x64 tile.
// ---------------------------------------------------------------------------
__global__ __launch_bounds__(256)
void gemm_ze(const _Float16* __restrict__ Ahi, const _Float16* __restrict__ Alo,
             const float* __restrict__ W, const float* __restrict__ bias,
             float* __restrict__ C, int M, int N, int K)
{
    __shared__ alignas(16) float As[16][64];
    __shared__ alignas(16) float Bs[16][64];

    const int tid = threadIdx.x;
    const int tx  = tid % 16;
    const int ty  = tid / 16;
    const int bm  = blockIdx.y * 64;
    const int bn  = blockIdx.x * 64;

    double acc[4][4];
#pragma unroll
    for (int i = 0; i < 4; ++i)
#pragma unroll
        for (int j = 0; j < 4; ++j) acc[i][j] = 0.0;

    for (int k0 = 0; k0 < K; k0 += 16) {
        {   // A stage from pairs
            int idx = tid * 4;
            int r = idx >> 4, c = idx & 15;
            f16x4 h = *reinterpret_cast<const f16x4*>(&Ahi[(size_t)(bm + r) * K + k0 + c]);
            f16x4 l = *reinterpret_cast<const f16x4*>(&Alo[(size_t)(bm + r) * K + k0 + c]);
#pragma unroll
            for (int i = 0; i < 4; ++i)
                As[c + i][r] = (float)h[i] + 2.44140625e-4f * (float)l[i];
        }
        {   // B stage (fp32 W)
            int idx = tid * 4;
            int r = idx / 64, c = idx % 64;
            *reinterpret_cast<float4*>(&Bs[r][c]) =
                *reinterpret_cast<const float4*>(&W[(size_t)(k0 + r) * N + bn + c]);
        }
        __syncthreads();

#pragma unroll
        for (int kk = 0; kk < 16; ++kk) {
            float a[4], b[4];
#pragma unroll
            for (int i = 0; i < 4; ++i) a[i] = As[kk][ty * 4 + i];
#pragma unroll
            for (int j = 0; j < 4; ++j) b[j] = Bs[kk][tx * 4 + j];
#pragma unroll
            for (int i = 0; i < 4; ++i)
#pragma unroll
                for (int j = 0; j < 4; ++j)
                    acc[i][j] = fma((double)a[i], (double)b[j], acc[i][j]);
        }
        __syncthreads();
    }

#pragma unroll
    for (int ii = 0; ii < 4; ++ii) {
        const size_t r = (size_t)bm + ty * 4 + ii;
        const int c = bn + tx * 4;
        float4 bv = *reinterpret_cast<const float4*>(&bias[c]);
        float4 o;
        o.x = (float)acc[ii][0] + bv.x; o.y = (float)acc[ii][1] + bv.y;
        o.z = (float)acc[ii][2] + bv.z; o.w = (float)acc[ii][3] + bv.w;
        *reinterpret_cast<float4*>(&C[r * N + c]) = o;
    }
}

// ---------------------------------------------------------------------------
// bf16 MFMA GEMM (decoder): C[M,N] = op(A[M,K] @ Bt[N,K]^T + bias).
// ---------------------------------------------------------------------------
template<bool RELU, bool OUT_BF16>
__global__ __launch_bounds__(256)
void gemm_mfma_bt(const unsigned short* __restrict__ A,
                  const unsigned short* __restrict__ Bt,
                  const float* __restrict__ bias,
                  void* __restrict__ Cv, int M, int N, int K)
{
    constexpr int BK  = 64;
    constexpr int LDP = BK + 8;

    __shared__ alignas(16) unsigned short Asl[128][LDP];
    __shared__ alignas(16) unsigned short Bsl[128][LDP];

    const int tid  = threadIdx.x;
    const int lane = tid & 63;
    const int w    = tid >> 6;
    const int wr   = (w >> 1) * 64;
    const int wc   = (w & 1) * 64;
    const int bm   = blockIdx.y * 128;
    const int bn   = blockIdx.x * 128;

    f32x4 acc[4][4];
#pragma unroll
    for (int m = 0; m < 4; ++m)
#pragma unroll
        for (int n = 0; n < 4; ++n) acc[m][n] = (f32x4){0.f, 0.f, 0.f, 0.f};

    const int sr = tid >> 1;
    const int sc = (tid & 1) * 32;

    for (int k0 = 0; k0 < K; k0 += BK) {
        {
            const float4* ga = reinterpret_cast<const float4*>(
                &A[(size_t)(bm + sr) * K + k0 + sc]);
            const float4* gb = reinterpret_cast<const float4*>(
                &Bt[(size_t)(bn + sr) * K + k0 + sc]);
            float4 va0 = ga[0], va1 = ga[1], va2 = ga[2], va3 = ga[3];
            float4 vb0 = gb[0], vb1 = gb[1], vb2 = gb[2], vb3 = gb[3];
            float4* da = reinterpret_cast<float4*>(&Asl[sr][sc]);
            float4* db = reinterpret_cast<float4*>(&Bsl[sr][sc]);
            da[0] = va0; da[1] = va1; da[2] = va2; da[3] = va3;
            db[0] = vb0; db[1] = vb1; db[2] = vb2; db[3] = vb3;
        }
        __syncthreads();

#pragma unroll
        for (int ks = 0; ks < 2; ++ks) {
            bf16x8 af[4], bf[4];
            const int kc = ks * 32 + (lane >> 4) * 8;
#pragma unroll
            for (int m = 0; m < 4; ++m)
                af[m] = *reinterpret_cast<const bf16x8*>(
                    &Asl[wr + m * 16 + (lane & 15)][kc]);
#pragma unroll
            for (int n = 0; n < 4; ++n)
                bf[n] = *reinterpret_cast<const bf16x8*>(
                    &Bsl[wc + n * 16 + (lane & 15)][kc]);
#pragma unroll
            for (int m = 0; m < 4; ++m)
#pragma unroll
                for (int n = 0; n < 4; ++n)
                    acc[m][n] = __builtin_amdgcn_mfma_f32_16x16x32_bf16(
                        af[m], bf[n], acc[m][n], 0, 0, 0);
        }
        __syncthreads();
    }

#pragma unroll
    for (int m = 0; m < 4; ++m)
#pragma unroll
        for (int n = 0; n < 4; ++n) {
            const int col = bn + wc + n * 16 + (lane & 15);
            const float bv = bias[col];
#pragma unroll
            for (int q = 0; q < 4; ++q) {
                const int row = bm + wr + m * 16 + (lane >> 4) * 4 + q;
                float v = acc[m][n][q] + bv;
                if (RELU) v = fmaxf(v, 0.f);
                if (OUT_BF16)
                    reinterpret_cast<unsigned short*>(Cv)[(size_t)row * N + col] = f2bf(v);
                else
                    reinterpret_cast<float*>(Cv)[(size_t)row * N + col] = v;
            }
        }
}

// ---------------------------------------------------------------------------
// small prep kernels
// ---------------------------------------------------------------------------
__global__ __launch_bounds__(256)
void transpose_bf16(const float* __restrict__ W, unsigned short* __restrict__ Wt,
                    int K, int N)
{
    int idx = blockIdx.x * 256 + threadIdx.x;
    if (idx >= K * N) return;
    int n = idx / K, k = idx % K;
    Wt[idx] = f2bf(W[(size_t)k * N + n]);
}

__global__ __launch_bounds__(256)
void transpose_split_f16(const float* __restrict__ W,
                         _Float16* __restrict__ Whi, _Float16* __restrict__ Wlo,
                         int K, int N)
{
    int idx = blockIdx.x * 256 + threadIdx.x;
    if (idx >= K * N) return;
    int n = idx / K, k = idx % K;
    _Float16 hi, lo; fsplit(W[(size_t)k * N + n], hi, lo);
    Whi[idx] = hi; Wlo[idx] = lo;
}

__global__ __launch_bounds__(256)
void split_f16(const float* __restrict__ src,
               _Float16* __restrict__ hi, _Float16* __restrict__ lo, int n8)
{
    int i = blockIdx.x * 256 + threadIdx.x;
    if (i >= n8) return;
    float4 a = *reinterpret_cast<const float4*>(&src[i * 8]);
    float4 b = *reinterpret_cast<const float4*>(&src[i * 8 + 4]);
    _Float16 h[8], l[8];
    fsplit(a.x, h[0], l[0]); fsplit(a.y, h[1], l[1]);
    fsplit(a.z, h[2], l[2]); fsplit(a.w, h[3], l[3]);
    fsplit(b.x, h[4], l[4]); fsplit(b.y, h[5], l[5]);
    fsplit(b.z, h[6], l[6]); fsplit(b.w, h[7], l[7]);
    *reinterpret_cast<float4*>(&hi[i * 8]) = *reinterpret_cast<float4*>(h);
    *reinterpret_cast<float4*>(&lo[i * 8]) = *reinterpret_cast<float4*>(l);
}

// ---------------------------------------------------------------------------
// VQ: exact (fp64) nearest-codebook + gather; also emits bf16 z_q copy.
// ---------------------------------------------------------------------------
__global__ __launch_bounds__(256)
void vq_gather(const float* __restrict__ Z, const float* __restrict__ CB,
               float* __restrict__ OUT, unsigned short* __restrict__ ZQB, int M)
{
    __shared__ alignas(16) float cb[256 * 64];
    __shared__ double ccs[256];

    const int tid = threadIdx.x;
    const int row = blockIdx.x * 256 + tid;

#pragma unroll
    for (int v = 0; v < 16; ++v) {
        int idx = (tid + v * 256) * 4;
        *reinterpret_cast<float4*>(&cb[idx]) =
            *reinterpret_cast<const float4*>(&CB[idx]);
    }
    __syncthreads();

    {
        double cc = 0.0;
        const float* c = &cb[tid * 64];
#pragma unroll
        for (int d = 0; d < 64; ++d) { double cd = (double)c[d]; cc = fma(cd, cd, cc); }
        ccs[tid] = cc;
    }

    float z[64];
#pragma unroll
    for (int v = 0; v < 16; ++v) {
        float4 f = *reinterpret_cast<const float4*>(&Z[(size_t)row * 64 + v * 4]);
        z[v * 4 + 0] = f.x; z[v * 4 + 1] = f.y; z[v * 4 + 2] = f.z; z[v * 4 + 3] = f.w;
    }
    double xx = 0.0;
#pragma unroll
    for (int d = 0; d < 64; ++d) { double zd = (double)z[d]; xx = fma(zd, zd, xx); }
    __syncthreads();

    double best = 1.0e300;
    int    bi   = 0;
    for (int e = 0; e < 256; ++e) {
        const float4* c4 = reinterpret_cast<const float4*>(&cb[e * 64]);
        double dot = 0.0;
#pragma unroll
        for (int v = 0; v < 16; ++v) {
            float4 f = c4[v];
            dot = fma((double)z[v * 4 + 0], (double)f.x, dot);
            dot = fma((double)z[v * 4 + 1], (double)f.y, dot);
            dot = fma((double)z[v * 4 + 2], (double)f.z, dot);
            dot = fma((double)z[v * 4 + 3], (double)f.w, dot);
        }
        double d2 = (xx - 2.0 * dot) + ccs[e];
        if (d2 < best) { best = d2; bi = e; }
    }

    {
        const float* src = &cb[bi * 64];
        float* dst = &OUT[(size_t)row * 64];
        unsigned short* dq = &ZQB[(size_t)row * 64];
#pragma unroll
        for (int v = 0; v < 16; ++v) {
            float4 f = *reinterpret_cast<const float4*>(src + v * 4);
            *reinterpret_cast<float4*>(dst + v * 4) = f;
            ushort4 qb = { f2bf(f.x), f2bf(f.y), f2bf(f.z), f2bf(f.w) };
            *reinterpret_cast<ushort4*>(dq + v * 4) = qb;
        }
    }
}

// ---------------------------------------------------------------------------
extern "C" void kernel_launch(void* const* d_in, const int* in_sizes, int n_in,
                              void* d_out, int out_size, void* d_ws, size_t ws_size,
                              hipStream_t stream)
{
    const float* X  = (const float*)d_in[0];
    const float* W0 = (const float*)d_in[1];
    const float* b0 = (const float*)d_in[2];
    const float* W1 = (const float*)d_in[3];
    const float* b1 = (const float*)d_in[4];
    const float* W2 = (const float*)d_in[5];
    const float* b2 = (const float*)d_in[6];
    const float* CB = (const float*)d_in[7];
    const float* W3 = (const float*)d_in[8];
    const float* b3 = (const float*)d_in[9];
    const float* W4 = (const float*)d_in[10];
    const float* b4 = (const float*)d_in[11];
    const float* W5 = (const float*)d_in[12];
    const float* b5 = (const float*)d_in[13];

    const int D_in = 256, H = 512, R = 64, S = 512, NA = 8;
    const int Mtot = in_sizes[0] / D_in;          // 131072

    float* recon = (float*)d_out;
    float* ze    = recon + (size_t)(Mtot / NA) * S;
    float* remb  = ze + (size_t)Mtot * R;

    // ---- workspace: fixed weight planes ----
    char* p = (char*)d_ws;
    _Float16* W0hi = (_Float16*)p;  p += (size_t)H * D_in * 2;      // [512,256]
    _Float16* W0lo = (_Float16*)p;  p += (size_t)H * D_in * 2;
    _Float16* W1hi = (_Float16*)p;  p += (size_t)H * H * 2;         // [512,512]
    _Float16* W1lo = (_Float16*)p;  p += (size_t)H * H * 2;
    unsigned short* W3t = (unsigned short*)p;  p += (size_t)H * R * 2;
    unsigned short* W4t = (unsigned short*)p;  p += (size_t)H * (NA * H) * 2;
    unsigned short* W5t = (unsigned short*)p;  p += (size_t)S * H * 2;
    size_t fixed = (size_t)(p - (char*)d_ws);
    fixed = (fixed + 255) & ~(size_t)255;

    // per-row chunk bytes: Xsp 1024 + h0 pair 2048 + h1 pair 2048 + zqb 128
    int nc = 2;
    while (nc < 128) {
        size_t rpcT = (size_t)Mtot / nc;
        if (fixed + rpcT * 5248 + 1024 <= ws_size) break;
        nc *= 2;
    }
    const int rpc = Mtot / nc;
    char* q = (char*)d_ws + fixed;
    _Float16* Xhi  = (_Float16*)q;                 q += (size_t)rpc * D_in * 2;
    _Float16* Xlo  = (_Float16*)q;                 q += (size_t)rpc * D_in * 2;
    _Float16* h0hi = (_Float16*)q;                 q += (size_t)rpc * H * 2;
    _Float16* h0lo = (_Float16*)q;                 q += (size_t)rpc * H * 2;
    _Float16* h1hi = (_Float16*)q;                 q += (size_t)rpc * H * 2;
    _Float16* h1lo = (_Float16*)q;                 q += (size_t)rpc * H * 2;
    unsigned short* zqb = (unsigned short*)q;      q += (size_t)rpc * R * 2;
    unsigned short* rec1b = (unsigned short*)h0hi;     // alias (h0 dead after h1)
    unsigned short* rec2b = (unsigned short*)h1hi;     // alias (h1 dead after z_e)

    // ---- one-time weight prep ----
    transpose_split_f16<<<(H * D_in + 255) / 256, 256, 0, stream>>>(W0, W0hi, W0lo, D_in, H);
    transpose_split_f16<<<(H * H + 255) / 256, 256, 0, stream>>>(W1, W1hi, W1lo, H, H);
    transpose_bf16<<<(H * R + 255) / 256, 256, 0, stream>>>(W3, W3t, R, H);
    transpose_bf16<<<(H * NA * H + 255) / 256, 256, 0, stream>>>(W4, W4t, NA * H, H);
    transpose_bf16<<<(S * H + 255) / 256, 256, 0, stream>>>(W5, W5t, H, S);

    for (int r0 = 0; r0 < Mtot; r0 += rpc) {
        const int M6 = rpc / NA;
        // encoder: split-fp16 MFMA (fp32-grade products)
        split_f16<<<(rpc * D_in / 8 + 255) / 256, 256, 0, stream>>>(
            X + (size_t)r0 * D_in, Xhi, Xlo, rpc * D_in / 8);
        gemm_split_f16<<<dim3(H / 128, rpc / 128), 256, 0, stream>>>(
            Xhi, Xlo, W0hi, W0lo, b0, h0hi, h0lo, rpc, H, D_in);
        gemm_split_f16<<<dim3(H / 128, rpc / 128), 256, 0, stream>>>(
            h0hi, h0lo, W1hi, W1lo, b1, h1hi, h1lo, rpc, H, H);
        // z_e: fp64 accumulation -> output zone 1
        gemm_ze<<<dim3(1, rpc / 64), 256, 0, stream>>>(
            h1hi, h1lo, W2, b2, ze + (size_t)r0 * R, rpc, R, H);
        // exact VQ -> role_emb + bf16 z_q
        vq_gather<<<rpc / 256, 256, 0, stream>>>(
            ze + (size_t)r0 * R, CB, remb + (size_t)r0 * R, zqb, rpc);
        // decoder: bf16 MFMA
        gemm_mfma_bt<true, true><<<dim3(H / 128, rpc / 128), 256, 0, stream>>>(
            zqb, W3t, b3, rec1b, rpc, H, R);
        gemm_mfma_bt<true, true><<<dim3(H / 128, M6 / 128), 256, 0, stream>>>(
            rec1b, W4t, b4, rec2b, M6, H, NA * H);
        gemm_mfma_bt<false, false><<<dim3(S / 128, M6 / 128), 256, 0, stream>>>(
            rec2b, W5t, b5, recon + (size_t)(r0 / NA) * S, M6, S, H);
    }
}

// Round 5
// 1598.944 us; speedup vs baseline: 1.8754x; 1.0468x over previous
//
#include <hip/hip_runtime.h>
#include <hip/hip_bf16.h>
#include <cstddef>

__device__ __forceinline__ unsigned short f2bf(float f) {
    union { float f; unsigned int u; } v; v.f = f;
    unsigned int r = (v.u + 0x7fffu + ((v.u >> 16) & 1u)) >> 16;   // RNE
    return (unsigned short)r;
}

typedef __bf16    bf16x8 __attribute__((ext_vector_type(8)));
typedef float     f32x4  __attribute__((ext_vector_type(4)));
typedef _Float16  f16x8  __attribute__((ext_vector_type(8)));
typedef _Float16  f16x4  __attribute__((ext_vector_type(4)));

// fp32 -> fp16 (hi, lo*4096) split: hi + 2^-12*lo == v to ~2^-22 relative.
__device__ __forceinline__ void fsplit(float v, _Float16& hi, _Float16& lo) {
    hi = (_Float16)v;
    lo = (_Float16)((v - (float)hi) * 4096.0f);
}

// ---------------------------------------------------------------------------
// Split-fp16 MFMA GEMM v2 (encoder): C = relu(A @ Bt^T + bias).
// A (hi/lo planes) is streamed DIRECTLY from global into MFMA fragments --
// row-major-K means lane(l) reads 16B at A[row(l&15)][k+(l>>4)*8]; one wave
// covers 16 rows x 64B contiguous (L2-friendly, bm shared by 4 grid.x blocks).
// Only B hi/lo staged in LDS (20 KB, BK=32, rows padded to 40 f16 = 80B
// stride -> 2-way bank aliasing = free). 3 MFMA passes: acc0=Ah*Bh,
// acc1=Ah*Bl+Al*Bh, C = acc0 + 2^-12*acc1.
// ---------------------------------------------------------------------------
template<int K>
__global__ __launch_bounds__(256, 2)
void gemm_split2(const _Float16* __restrict__ Ahi, const _Float16* __restrict__ Alo,
                 const _Float16* __restrict__ Bhi, const _Float16* __restrict__ Blo,
                 const float* __restrict__ bias,
                 _Float16* __restrict__ Chi, _Float16* __restrict__ Clo,
                 int M, int N)
{
    constexpr int BK  = 32;
    constexpr int LDP = 40;                      // 80B row stride (2-way = free)

    __shared__ alignas(16) _Float16 Bh[128][LDP];
    __shared__ alignas(16) _Float16 Bl[128][LDP];

    const int tid  = threadIdx.x;
    const int lane = tid & 63;
    const int w    = tid >> 6;
    const int wr   = (w >> 1) * 64;
    const int wc   = (w & 1) * 64;
    const int bm   = blockIdx.y * 128;
    const int bn   = blockIdx.x * 128;

    f32x4 acc0[4][4], acc1[4][4];
#pragma unroll
    for (int m = 0; m < 4; ++m)
#pragma unroll
        for (int n = 0; n < 4; ++n) {
            acc0[m][n] = (f32x4){0.f, 0.f, 0.f, 0.f};
            acc1[m][n] = (f32x4){0.f, 0.f, 0.f, 0.f};
        }

    const int arow = bm + wr + (lane & 15);      // A-frag row for m=0
    const int kgrp = (lane >> 4) * 8;            // k sub-offset
    const int brow = tid >> 1;                   // B staging: 2 thr/row
    const int bcol = (tid & 1) * 16;             // 16 f16 (32B) each

#pragma unroll
    for (int k0 = 0; k0 < K; k0 += BK) {
        {   // stage B hi/lo tile (128 x 32)
            const size_t gb = (size_t)(bn + brow) * K + k0 + bcol;
            float4 h0v = *reinterpret_cast<const float4*>(Bhi + gb);
            float4 h1v = *reinterpret_cast<const float4*>(Bhi + gb + 8);
            float4 l0v = *reinterpret_cast<const float4*>(Blo + gb);
            float4 l1v = *reinterpret_cast<const float4*>(Blo + gb + 8);
            *reinterpret_cast<float4*>(&Bh[brow][bcol])     = h0v;
            *reinterpret_cast<float4*>(&Bh[brow][bcol + 8]) = h1v;
            *reinterpret_cast<float4*>(&Bl[brow][bcol])     = l0v;
            *reinterpret_cast<float4*>(&Bl[brow][bcol + 8]) = l1v;
        }
        __syncthreads();

        // A fragments direct from global (16B/lane, 16 rows x 64B per wave)
        f16x8 ah[4], al[4];
#pragma unroll
        for (int m = 0; m < 4; ++m) {
            const size_t ga = (size_t)(arow + m * 16) * K + k0 + kgrp;
            ah[m] = *reinterpret_cast<const f16x8*>(Ahi + ga);
            al[m] = *reinterpret_cast<const f16x8*>(Alo + ga);
        }

#pragma unroll
        for (int n = 0; n < 4; ++n) {
            const f16x8 bh = *reinterpret_cast<const f16x8*>(
                &Bh[wc + n * 16 + (lane & 15)][kgrp]);
            const f16x8 bl = *reinterpret_cast<const f16x8*>(
                &Bl[wc + n * 16 + (lane & 15)][kgrp]);
#pragma unroll
            for (int m = 0; m < 4; ++m)
                acc0[m][n] = __builtin_amdgcn_mfma_f32_16x16x32_f16(
                    ah[m], bh, acc0[m][n], 0, 0, 0);
#pragma unroll
            for (int m = 0; m < 4; ++m)
                acc1[m][n] = __builtin_amdgcn_mfma_f32_16x16x32_f16(
                    ah[m], bl, acc1[m][n], 0, 0, 0);
#pragma unroll
            for (int m = 0; m < 4; ++m)
                acc1[m][n] = __builtin_amdgcn_mfma_f32_16x16x32_f16(
                    al[m], bh, acc1[m][n], 0, 0, 0);
        }
        __syncthreads();
    }

    // epilogue: combine, bias, relu, write fp16 pair planes
#pragma unroll
    for (int m = 0; m < 4; ++m)
#pragma unroll
        for (int n = 0; n < 4; ++n) {
            const int col = bn + wc + n * 16 + (lane & 15);
            const float bv = bias[col];
#pragma unroll
            for (int q = 0; q < 4; ++q) {
                const int row = bm + wr + m * 16 + (lane >> 4) * 4 + q;
                float v = acc0[m][n][q] + 2.44140625e-4f * acc1[m][n][q] + bv;
                v = fmaxf(v, 0.f);
                _Float16 hi, lo; fsplit(v, hi, lo);
                Chi[(size_t)row * N + col] = hi;
                Clo[(size_t)row * N + col] = lo;
            }
        }
}

// ---------------------------------------------------------------------------
// z_e GEMM: fp64 accumulation (exact-at-fp32 -> safe VQ argmin + tight
// output-1 check). A consumed from fp16 pair planes, W2 fp32. 64x64 tile.
// ---------------------------------------------------------------------------
__global__ __launch_bounds__(256)
void gemm_ze(const _Float16* __restrict__ Ahi, const _Float16* __restrict__ Alo,
             const float* __restrict__ W, const float* __restrict__ bias,
             float* __restrict__ C, int M, int N, int K)
{
    __shared__ alignas(16) float As[16][64];
    __shared__ alignas(16) float Bs[16][64];

    const int tid = threadIdx.x;
    const int tx  = tid % 16;
    const int ty  = tid / 16;
    const int bm  = blockIdx.y * 64;
    const int bn  = blockIdx.x * 64;

    double acc[4][4];
#pragma unroll
    for (int i = 0; i < 4; ++i)
#pragma unroll
        for (int j = 0; j < 4; ++j) acc[i][j] = 0.0;

    for (int k0 = 0; k0 < K; k0 += 16) {
        {
            int idx = tid * 4;
            int r = idx >> 4, c = idx & 15;
            f16x4 h = *reinterpret_cast<const f16x4*>(&Ahi[(size_t)(bm + r) * K + k0 + c]);
            f16x4 l = *reinterpret_cast<const f16x4*>(&Alo[(size_t)(bm + r) * K + k0 + c]);
#pragma unroll
            for (int i = 0; i < 4; ++i)
                As[c + i][r] = (float)h[i] + 2.44140625e-4f * (float)l[i];
        }
        {
            int idx = tid * 4;
            int r = idx / 64, c = idx % 64;
            *reinterpret_cast<float4*>(&Bs[r][c]) =
                *reinterpret_cast<const float4*>(&W[(size_t)(k0 + r) * N + bn + c]);
        }
        __syncthreads();

#pragma unroll
        for (int kk = 0; kk < 16; ++kk) {
            float a[4], b[4];
#pragma unroll
            for (int i = 0; i < 4; ++i) a[i] = As[kk][ty * 4 + i];
#pragma unroll
            for (int j = 0; j < 4; ++j) b[j] = Bs[kk][tx * 4 + j];
#pragma unroll
            for (int i = 0; i < 4; ++i)
#pragma unroll
                for (int j = 0; j < 4; ++j)
                    acc[i][j] = fma((double)a[i], (double)b[j], acc[i][j]);
        }
        __syncthreads();
    }

#pragma unroll
    for (int ii = 0; ii < 4; ++ii) {
        const size_t r = (size_t)bm + ty * 4 + ii;
        const int c = bn + tx * 4;
        float4 bv = *reinterpret_cast<const float4*>(&bias[c]);
        float4 o;
        o.x = (float)acc[ii][0] + bv.x; o.y = (float)acc[ii][1] + bv.y;
        o.z = (float)acc[ii][2] + bv.z; o.w = (float)acc[ii][3] + bv.w;
        *reinterpret_cast<float4*>(&C[r * N + c]) = o;
    }
}

// ---------------------------------------------------------------------------
// bf16 MFMA GEMM (decoder): C[M,N] = op(A[M,K] @ Bt[N,K]^T + bias).
// ---------------------------------------------------------------------------
template<bool RELU, bool OUT_BF16>
__global__ __launch_bounds__(256)
void gemm_mfma_bt(const unsigned short* __restrict__ A,
                  const unsigned short* __restrict__ Bt,
                  const float* __restrict__ bias,
                  void* __restrict__ Cv, int M, int N, int K)
{
    constexpr int BK  = 64;
    constexpr int LDP = BK + 8;

    __shared__ alignas(16) unsigned short Asl[128][LDP];
    __shared__ alignas(16) unsigned short Bsl[128][LDP];

    const int tid  = threadIdx.x;
    const int lane = tid & 63;
    const int w    = tid >> 6;
    const int wr   = (w >> 1) * 64;
    const int wc   = (w & 1) * 64;
    const int bm   = blockIdx.y * 128;
    const int bn   = blockIdx.x * 128;

    f32x4 acc[4][4];
#pragma unroll
    for (int m = 0; m < 4; ++m)
#pragma unroll
        for (int n = 0; n < 4; ++n) acc[m][n] = (f32x4){0.f, 0.f, 0.f, 0.f};

    const int sr = tid >> 1;
    const int sc = (tid & 1) * 32;

    for (int k0 = 0; k0 < K; k0 += BK) {
        {
            const float4* ga = reinterpret_cast<const float4*>(
                &A[(size_t)(bm + sr) * K + k0 + sc]);
            const float4* gb = reinterpret_cast<const float4*>(
                &Bt[(size_t)(bn + sr) * K + k0 + sc]);
            float4 va0 = ga[0], va1 = ga[1], va2 = ga[2], va3 = ga[3];
            float4 vb0 = gb[0], vb1 = gb[1], vb2 = gb[2], vb3 = gb[3];
            float4* da = reinterpret_cast<float4*>(&Asl[sr][sc]);
            float4* db = reinterpret_cast<float4*>(&Bsl[sr][sc]);
            da[0] = va0; da[1] = va1; da[2] = va2; da[3] = va3;
            db[0] = vb0; db[1] = vb1; db[2] = vb2; db[3] = vb3;
        }
        __syncthreads();

#pragma unroll
        for (int ks = 0; ks < 2; ++ks) {
            bf16x8 af[4], bf[4];
            const int kc = ks * 32 + (lane >> 4) * 8;
#pragma unroll
            for (int m = 0; m < 4; ++m)
                af[m] = *reinterpret_cast<const bf16x8*>(
                    &Asl[wr + m * 16 + (lane & 15)][kc]);
#pragma unroll
            for (int n = 0; n < 4; ++n)
                bf[n] = *reinterpret_cast<const bf16x8*>(
                    &Bsl[wc + n * 16 + (lane & 15)][kc]);
#pragma unroll
            for (int m = 0; m < 4; ++m)
#pragma unroll
                for (int n = 0; n < 4; ++n)
                    acc[m][n] = __builtin_amdgcn_mfma_f32_16x16x32_bf16(
                        af[m], bf[n], acc[m][n], 0, 0, 0);
        }
        __syncthreads();
    }

#pragma unroll
    for (int m = 0; m < 4; ++m)
#pragma unroll
        for (int n = 0; n < 4; ++n) {
            const int col = bn + wc + n * 16 + (lane & 15);
            const float bv = bias[col];
#pragma unroll
            for (int q = 0; q < 4; ++q) {
                const int row = bm + wr + m * 16 + (lane >> 4) * 4 + q;
                float v = acc[m][n][q] + bv;
                if (RELU) v = fmaxf(v, 0.f);
                if (OUT_BF16)
                    reinterpret_cast<unsigned short*>(Cv)[(size_t)row * N + col] = f2bf(v);
                else
                    reinterpret_cast<float*>(Cv)[(size_t)row * N + col] = v;
            }
        }
}

// ---------------------------------------------------------------------------
// small prep kernels
// ---------------------------------------------------------------------------
__global__ __launch_bounds__(256)
void transpose_bf16(const float* __restrict__ W, unsigned short* __restrict__ Wt,
                    int K, int N)
{
    int idx = blockIdx.x * 256 + threadIdx.x;
    if (idx >= K * N) return;
    int n = idx / K, k = idx % K;
    Wt[idx] = f2bf(W[(size_t)k * N + n]);
}

__global__ __launch_bounds__(256)
void transpose_split_f16(const float* __restrict__ W,
                         _Float16* __restrict__ Whi, _Float16* __restrict__ Wlo,
                         int K, int N)
{
    int idx = blockIdx.x * 256 + threadIdx.x;
    if (idx >= K * N) return;
    int n = idx / K, k = idx % K;
    _Float16 hi, lo; fsplit(W[(size_t)k * N + n], hi, lo);
    Whi[idx] = hi; Wlo[idx] = lo;
}

__global__ __launch_bounds__(256)
void split_f16(const float* __restrict__ src,
               _Float16* __restrict__ hi, _Float16* __restrict__ lo, int n8)
{
    int i = blockIdx.x * 256 + threadIdx.x;
    if (i >= n8) return;
    float4 a = *reinterpret_cast<const float4*>(&src[i * 8]);
    float4 b = *reinterpret_cast<const float4*>(&src[i * 8 + 4]);
    _Float16 h[8], l[8];
    fsplit(a.x, h[0], l[0]); fsplit(a.y, h[1], l[1]);
    fsplit(a.z, h[2], l[2]); fsplit(a.w, h[3], l[3]);
    fsplit(b.x, h[4], l[4]); fsplit(b.y, h[5], l[5]);
    fsplit(b.z, h[6], l[6]); fsplit(b.w, h[7], l[7]);
    *reinterpret_cast<float4*>(&hi[i * 8]) = *reinterpret_cast<float4*>(h);
    *reinterpret_cast<float4*>(&lo[i * 8]) = *reinterpret_cast<float4*>(l);
}

// ---------------------------------------------------------------------------
// VQ: exact (fp64) nearest-codebook + gather; also emits bf16 z_q copy.
// ---------------------------------------------------------------------------
__global__ __launch_bounds__(256)
void vq_gather(const float* __restrict__ Z, const float* __restrict__ CB,
               float* __restrict__ OUT, unsigned short* __restrict__ ZQB, int M)
{
    __shared__ alignas(16) float cb[256 * 64];
    __shared__ double ccs[256];

    const int tid = threadIdx.x;
    const int row = blockIdx.x * 256 + tid;

#pragma unroll
    for (int v = 0; v < 16; ++v) {
        int idx = (tid + v * 256) * 4;
        *reinterpret_cast<float4*>(&cb[idx]) =
            *reinterpret_cast<const float4*>(&CB[idx]);
    }
    __syncthreads();

    {
        double cc = 0.0;
        const float* c = &cb[tid * 64];
#pragma unroll
        for (int d = 0; d < 64; ++d) { double cd = (double)c[d]; cc = fma(cd, cd, cc); }
        ccs[tid] = cc;
    }

    float z[64];
#pragma unroll
    for (int v = 0; v < 16; ++v) {
        float4 f = *reinterpret_cast<const float4*>(&Z[(size_t)row * 64 + v * 4]);
        z[v * 4 + 0] = f.x; z[v * 4 + 1] = f.y; z[v * 4 + 2] = f.z; z[v * 4 + 3] = f.w;
    }
    double xx = 0.0;
#pragma unroll
    for (int d = 0; d < 64; ++d) { double zd = (double)z[d]; xx = fma(zd, zd, xx); }
    __syncthreads();

    double best = 1.0e300;
    int    bi   = 0;
    for (int e = 0; e < 256; ++e) {
        const float4* c4 = reinterpret_cast<const float4*>(&cb[e * 64]);
        double dot = 0.0;
#pragma unroll
        for (int v = 0; v < 16; ++v) {
            float4 f = c4[v];
            dot = fma((double)z[v * 4 + 0], (double)f.x, dot);
            dot = fma((double)z[v * 4 + 1], (double)f.y, dot);
            dot = fma((double)z[v * 4 + 2], (double)f.z, dot);
            dot = fma((double)z[v * 4 + 3], (double)f.w, dot);
        }
        double d2 = (xx - 2.0 * dot) + ccs[e];
        if (d2 < best) { best = d2; bi = e; }
    }

    {
        const float* src = &cb[bi * 64];
        float* dst = &OUT[(size_t)row * 64];
        unsigned short* dq = &ZQB[(size_t)row * 64];
#pragma unroll
        for (int v = 0; v < 16; ++v) {
            float4 f = *reinterpret_cast<const float4*>(src + v * 4);
            *reinterpret_cast<float4*>(dst + v * 4) = f;
            ushort4 qb = { f2bf(f.x), f2bf(f.y), f2bf(f.z), f2bf(f.w) };
            *reinterpret_cast<ushort4*>(dq + v * 4) = qb;
        }
    }
}

// ---------------------------------------------------------------------------
extern "C" void kernel_launch(void* const* d_in, const int* in_sizes, int n_in,
                              void* d_out, int out_size, void* d_ws, size_t ws_size,
                              hipStream_t stream)
{
    const float* X  = (const float*)d_in[0];
    const float* W0 = (const float*)d_in[1];
    const float* b0 = (const float*)d_in[2];
    const float* W1 = (const float*)d_in[3];
    const float* b1 = (const float*)d_in[4];
    const float* W2 = (const float*)d_in[5];
    const float* b2 = (const float*)d_in[6];
    const float* CB = (const float*)d_in[7];
    const float* W3 = (const float*)d_in[8];
    const float* b3 = (const float*)d_in[9];
    const float* W4 = (const float*)d_in[10];
    const float* b4 = (const float*)d_in[11];
    const float* W5 = (const float*)d_in[12];
    const float* b5 = (const float*)d_in[13];

    const int D_in = 256, H = 512, R = 64, S = 512, NA = 8;
    const int Mtot = in_sizes[0] / D_in;          // 131072

    float* recon = (float*)d_out;
    float* ze    = recon + (size_t)(Mtot / NA) * S;
    float* remb  = ze + (size_t)Mtot * R;

    // ---- workspace: fixed weight planes ----
    char* p = (char*)d_ws;
    _Float16* W0hi = (_Float16*)p;  p += (size_t)H * D_in * 2;
    _Float16* W0lo = (_Float16*)p;  p += (size_t)H * D_in * 2;
    _Float16* W1hi = (_Float16*)p;  p += (size_t)H * H * 2;
    _Float16* W1lo = (_Float16*)p;  p += (size_t)H * H * 2;
    unsigned short* W3t = (unsigned short*)p;  p += (size_t)H * R * 2;
    unsigned short* W4t = (unsigned short*)p;  p += (size_t)H * (NA * H) * 2;
    unsigned short* W5t = (unsigned short*)p;  p += (size_t)S * H * 2;
    size_t fixed = (size_t)(p - (char*)d_ws);
    fixed = (fixed + 255) & ~(size_t)255;

    // per-row chunk bytes: X pair 1024 + h0 pair 2048 + h1 pair 2048 + zqb 128
    int nc = 2;
    while (nc < 128) {
        size_t rpcT = (size_t)Mtot / nc;
        if (fixed + rpcT * 5248 + 1024 <= ws_size) break;
        nc *= 2;
    }
    const int rpc = Mtot / nc;
    char* q = (char*)d_ws + fixed;
    _Float16* Xhi  = (_Float16*)q;                 q += (size_t)rpc * D_in * 2;
    _Float16* Xlo  = (_Float16*)q;                 q += (size_t)rpc * D_in * 2;
    _Float16* h0hi = (_Float16*)q;                 q += (size_t)rpc * H * 2;
    _Float16* h0lo = (_Float16*)q;                 q += (size_t)rpc * H * 2;
    _Float16* h1hi = (_Float16*)q;                 q += (size_t)rpc * H * 2;
    _Float16* h1lo = (_Float16*)q;                 q += (size_t)rpc * H * 2;
    unsigned short* zqb = (unsigned short*)q;      q += (size_t)rpc * R * 2;
    unsigned short* rec1b = (unsigned short*)h0hi;     // alias (h0 dead after h1)
    unsigned short* rec2b = (unsigned short*)h1hi;     // alias (h1 dead after z_e)

    // ---- one-time weight prep ----
    transpose_split_f16<<<(H * D_in + 255) / 256, 256, 0, stream>>>(W0, W0hi, W0lo, D_in, H);
    transpose_split_f16<<<(H * H + 255) / 256, 256, 0, stream>>>(W1, W1hi, W1lo, H, H);
    transpose_bf16<<<(H * R + 255) / 256, 256, 0, stream>>>(W3, W3t, R, H);
    transpose_bf16<<<(H * NA * H + 255) / 256, 256, 0, stream>>>(W4, W4t, NA * H, H);
    transpose_bf16<<<(S * H + 255) / 256, 256, 0, stream>>>(W5, W5t, H, S);

    for (int r0 = 0; r0 < Mtot; r0 += rpc) {
        const int M6 = rpc / NA;
        // encoder: split-fp16 MFMA, A streamed from global
        split_f16<<<(rpc * D_in / 8 + 255) / 256, 256, 0, stream>>>(
            X + (size_t)r0 * D_in, Xhi, Xlo, rpc * D_in / 8);
        gemm_split2<256><<<dim3(H / 128, rpc / 128), 256, 0, stream>>>(
            Xhi, Xlo, W0hi, W0lo, b0, h0hi, h0lo, rpc, H);
        gemm_split2<512><<<dim3(H / 128, rpc / 128), 256, 0, stream>>>(
            h0hi, h0lo, W1hi, W1lo, b1, h1hi, h1lo, rpc, H);
        // z_e: fp64 accumulation -> output zone 1
        gemm_ze<<<dim3(1, rpc / 64), 256, 0, stream>>>(
            h1hi, h1lo, W2, b2, ze + (size_t)r0 * R, rpc, R, H);
        // exact VQ -> role_emb + bf16 z_q
        vq_gather<<<rpc / 256, 256, 0, stream>>>(
            ze + (size_t)r0 * R, CB, remb + (size_t)r0 * R, zqb, rpc);
        // decoder: bf16 MFMA
        gemm_mfma_bt<true, true><<<dim3(H / 128, rpc / 128), 256, 0, stream>>>(
            zqb, W3t, b3, rec1b, rpc, H, R);
        gemm_mfma_bt<true, true><<<dim3(H / 128, M6 / 128), 256, 0, stream>>>(
            rec1b, W4t, b4, rec2b, M6, H, NA * H);
        gemm_mfma_bt<false, false><<<dim3(S / 128, M6 / 128), 256, 0, stream>>>(
            rec2b, W5t, b5, recon + (size_t)(r0 / NA) * S, M6, S, H);
    }
}